// Round 6
// baseline (213.794 us; speedup 1.0000x reference)
//
#include <hip/hip_runtime.h>

#define R_ 512
#define K_ 250
#define SK 20   // s_k/s_v/s_x row stride in floats (80B): 8 consecutive rows -> 8 distinct 16B slots, conflict-free
#define SCALE_LOG2E 0.72134752044448170f

#define ATT_STEP(KP, VP) do {                                                        \
    const float4 k0 = ((const float4*)(KP))[0];                                      \
    const float4 k1 = ((const float4*)(KP))[1];                                      \
    const float4 k2 = ((const float4*)(KP))[2];                                      \
    const float4 k3 = ((const float4*)(KP))[3];                                      \
    float s00 = fmaf(q0[0],k0.x, fmaf(q0[1],k0.y, fmaf(q0[2],k0.z, q0[3]*k0.w)));    \
    float s01 = fmaf(q0[4],k1.x, fmaf(q0[5],k1.y, fmaf(q0[6],k1.z, q0[7]*k1.w)));    \
    float s02 = fmaf(q0[8],k2.x, fmaf(q0[9],k2.y, fmaf(q0[10],k2.z, q0[11]*k2.w)));  \
    float s03 = fmaf(q0[12],k3.x, fmaf(q0[13],k3.y, fmaf(q0[14],k3.z, q0[15]*k3.w)));\
    float s10 = fmaf(q1[0],k0.x, fmaf(q1[1],k0.y, fmaf(q1[2],k0.z, q1[3]*k0.w)));    \
    float s11 = fmaf(q1[4],k1.x, fmaf(q1[5],k1.y, fmaf(q1[6],k1.z, q1[7]*k1.w)));    \
    float s12 = fmaf(q1[8],k2.x, fmaf(q1[9],k2.y, fmaf(q1[10],k2.z, q1[11]*k2.w)));  \
    float s13 = fmaf(q1[12],k3.x, fmaf(q1[13],k3.y, fmaf(q1[14],k3.z, q1[15]*k3.w)));\
    const float p00 = __builtin_amdgcn_exp2f(s00);                                   \
    const float p01 = __builtin_amdgcn_exp2f(s01);                                   \
    const float p02 = __builtin_amdgcn_exp2f(s02);                                   \
    const float p03 = __builtin_amdgcn_exp2f(s03);                                   \
    const float p10 = __builtin_amdgcn_exp2f(s10);                                   \
    const float p11 = __builtin_amdgcn_exp2f(s11);                                   \
    const float p12 = __builtin_amdgcn_exp2f(s12);                                   \
    const float p13 = __builtin_amdgcn_exp2f(s13);                                   \
    const float4 v0 = ((const float4*)(VP))[0];                                      \
    const float4 v1 = ((const float4*)(VP))[1];                                      \
    const float4 v2 = ((const float4*)(VP))[2];                                      \
    const float4 v3 = ((const float4*)(VP))[3];                                      \
    ls0 += p00; ls1 += p01; ls2 += p02; ls3 += p03;                                  \
    ls4 += p10; ls5 += p11; ls6 += p12; ls7 += p13;                                  \
    acc0[0]  = fmaf(p00, v0.x, acc0[0]);  acc0[1]  = fmaf(p00, v0.y, acc0[1]);       \
    acc0[2]  = fmaf(p00, v0.z, acc0[2]);  acc0[3]  = fmaf(p00, v0.w, acc0[3]);       \
    acc0[4]  = fmaf(p01, v1.x, acc0[4]);  acc0[5]  = fmaf(p01, v1.y, acc0[5]);       \
    acc0[6]  = fmaf(p01, v1.z, acc0[6]);  acc0[7]  = fmaf(p01, v1.w, acc0[7]);       \
    acc0[8]  = fmaf(p02, v2.x, acc0[8]);  acc0[9]  = fmaf(p02, v2.y, acc0[9]);       \
    acc0[10] = fmaf(p02, v2.z, acc0[10]); acc0[11] = fmaf(p02, v2.w, acc0[11]);      \
    acc0[12] = fmaf(p03, v3.x, acc0[12]); acc0[13] = fmaf(p03, v3.y, acc0[13]);      \
    acc0[14] = fmaf(p03, v3.z, acc0[14]); acc0[15] = fmaf(p03, v3.w, acc0[15]);      \
    acc1[0]  = fmaf(p10, v0.x, acc1[0]);  acc1[1]  = fmaf(p10, v0.y, acc1[1]);       \
    acc1[2]  = fmaf(p10, v0.z, acc1[2]);  acc1[3]  = fmaf(p10, v0.w, acc1[3]);       \
    acc1[4]  = fmaf(p11, v1.x, acc1[4]);  acc1[5]  = fmaf(p11, v1.y, acc1[5]);       \
    acc1[6]  = fmaf(p11, v1.z, acc1[6]);  acc1[7]  = fmaf(p11, v1.w, acc1[7]);       \
    acc1[8]  = fmaf(p12, v2.x, acc1[8]);  acc1[9]  = fmaf(p12, v2.y, acc1[9]);       \
    acc1[10] = fmaf(p12, v2.z, acc1[10]); acc1[11] = fmaf(p12, v2.w, acc1[11]);      \
    acc1[12] = fmaf(p13, v3.x, acc1[12]); acc1[13] = fmaf(p13, v3.y, acc1[13]);      \
    acc1[14] = fmaf(p13, v3.z, acc1[14]); acc1[15] = fmaf(p13, v3.w, acc1[15]);      \
} while (0)

// PASS 0: x built from raw inputs, result x' -> xout (workspace)
// PASS 1: x loaded from xin (workspace), result -> xout (final output)
// grid: 1024 blocks = (range r, query-half s); block handles queries [125s, 125s+126)
template<int PASS>
__global__ __launch_bounds__(512, 2)
void mlra_pass(const float* __restrict__ pv,       // [R*K,8]
               const int*   __restrict__ ele_idx,  // [R*K]
               const int*   __restrict__ azi_idx,  // [R*K]
               const float* __restrict__ vp_w,     // [8,8]
               const float* __restrict__ vp_b,     // [8]
               const float* __restrict__ ele_emb,  // [37,4]
               const float* __restrict__ azi_emb,  // [107,4]
               const float* __restrict__ ipw,      // [2,48,16]
               const float* __restrict__ ipb,      // [2,48]
               const float* __restrict__ outw,     // [2,16,16]
               const float* __restrict__ outb,     // [2,16]
               const float* __restrict__ lng,      // [16]
               const float* __restrict__ lnb,      // [16]
               const float* __restrict__ xin,      // [R*K,16] (PASS 1)
               float* __restrict__ xout)           // [R*K,16]
{
    __shared__ float s_k[K_][SK];       // 20000 B
    __shared__ float s_v[K_][SK];       // 20000 B
    __shared__ float s_x[252][SK];      // 20160 B
    __shared__ float s_w[768];
    __shared__ float s_b[48];
    __shared__ float s_ow[256];
    __shared__ float s_ob[16];
    __shared__ float s_vpw[64];
    __shared__ float s_vpb[8];
    __shared__ float s_ele[148];
    __shared__ float s_azi[428];
    __shared__ float s_lng[16], s_lnb[16];

    const int r = blockIdx.x >> 1;
    const int s = blockIdx.x & 1;
    const int t = threadIdx.x;

    // ---- stage layer weights (+ tables for PASS 0) ----
    for (int i = t; i < 768; i += 512) s_w[i] = ipw[PASS*768 + i];
    if (t < 48)  s_b[t]  = ipb[PASS*48 + t];
    if (t < 256) s_ow[t] = outw[PASS*256 + t];
    if (t < 16)  s_ob[t] = outb[PASS*16 + t];
    if (t < 16)  { s_lng[t] = lng[t]; s_lnb[t] = lnb[t]; }
    if (PASS == 0) {
        if (t >= 64 && t < 128) s_vpw[t-64] = vp_w[t-64];
        if (t >= 128 && t < 136) s_vpb[t-128] = vp_b[t-128];
        for (int i = t; i < 148; i += 512) s_ele[i] = ele_emb[i];
        for (int i = t; i < 428; i += 512) s_azi[i] = azi_emb[i];
    }
    __syncthreads();

    // ---- x rows 0..249 into s_x (build for PASS 0, load for PASS 1) ----
    if (t < K_) {
        float xr[16];
        if (PASS == 0) {
            const size_t row = (size_t)r * K_ + t;
            const float4 p0 = ((const float4*)(pv + row * 8))[0];
            const float4 p1 = ((const float4*)(pv + row * 8))[1];
            const float a[8] = {p0.x,p0.y,p0.z,p0.w,p1.x,p1.y,p1.z,p1.w};
            #pragma unroll
            for (int o = 0; o < 8; ++o) {
                const float4 w0 = ((const float4*)&s_vpw[o*8])[0];
                const float4 w1 = ((const float4*)&s_vpw[o*8])[1];
                float sv = s_vpb[o];
                sv = fmaf(a[0],w0.x,sv); sv = fmaf(a[1],w0.y,sv); sv = fmaf(a[2],w0.z,sv); sv = fmaf(a[3],w0.w,sv);
                sv = fmaf(a[4],w1.x,sv); sv = fmaf(a[5],w1.y,sv); sv = fmaf(a[6],w1.z,sv); sv = fmaf(a[7],w1.w,sv);
                xr[o] = sv;
            }
            const int ei = ele_idx[row];
            const int ai = azi_idx[row];
            const float4 ee = *(const float4*)&s_ele[ei*4];
            const float4 ae = *(const float4*)&s_azi[ai*4];
            xr[8]=ee.x; xr[9]=ee.y; xr[10]=ee.z; xr[11]=ee.w;
            xr[12]=ae.x; xr[13]=ae.y; xr[14]=ae.z; xr[15]=ae.w;
        } else {
            const float4* src = (const float4*)(xin + ((size_t)r * K_ + t) * 16);
            const float4 a0 = src[0], a1 = src[1], a2 = src[2], a3 = src[3];
            xr[0]=a0.x; xr[1]=a0.y; xr[2]=a0.z; xr[3]=a0.w;
            xr[4]=a1.x; xr[5]=a1.y; xr[6]=a1.z; xr[7]=a1.w;
            xr[8]=a2.x; xr[9]=a2.y; xr[10]=a2.z; xr[11]=a2.w;
            xr[12]=a3.x; xr[13]=a3.y; xr[14]=a3.z; xr[15]=a3.w;
        }
        float4* xd = (float4*)&s_x[t][0];
        xd[0] = make_float4(xr[0],xr[1],xr[2],xr[3]);
        xd[1] = make_float4(xr[4],xr[5],xr[6],xr[7]);
        xd[2] = make_float4(xr[8],xr[9],xr[10],xr[11]);
        xd[3] = make_float4(xr[12],xr[13],xr[14],xr[15]);
    } else if (t < 252 + 6) {
        // zero pad rows 250,251 (row 250 is read by the masked tail query pair)
        if (t >= 256 && t < 258) {
            float4* xd = (float4*)&s_x[250 + (t - 256)][0];
            xd[0] = xd[1] = xd[2] = xd[3] = make_float4(0.f,0.f,0.f,0.f);
        }
    }
    __syncthreads();

    // thread = (qpair qp<63, eighth e<8); query rows a=qbase+2qp, b=a+1
    const int  qp    = t >> 3;
    const int  e     = t & 7;
    const bool qact  = qp < 63;
    const int  qbase = s * 125;
    const int  arow  = qbase + 2*qp;
    const int  brow  = arow + 1;              // == 250 only for s=1,qp=62 (masked)
    const bool bval  = brow < K_;
    const int  od    = 2*e;                   // this lane's 2 output dims

    // ---- QKV phase: q0,q1 in regs; every thread also computes one K or V row ----
    float q0[16], q1[16];
    if (qact) {
        float x0[16], x1[16];
        {
            const float4* xa = (const float4*)&s_x[arow][0];
            const float4 a0 = xa[0], a1 = xa[1], a2 = xa[2], a3 = xa[3];
            x0[0]=a0.x; x0[1]=a0.y; x0[2]=a0.z; x0[3]=a0.w;
            x0[4]=a1.x; x0[5]=a1.y; x0[6]=a1.z; x0[7]=a1.w;
            x0[8]=a2.x; x0[9]=a2.y; x0[10]=a2.z; x0[11]=a2.w;
            x0[12]=a3.x; x0[13]=a3.y; x0[14]=a3.z; x0[15]=a3.w;
            const float4* xb = (const float4*)&s_x[brow][0];
            const float4 b0 = xb[0], b1 = xb[1], b2 = xb[2], b3 = xb[3];
            x1[0]=b0.x; x1[1]=b0.y; x1[2]=b0.z; x1[3]=b0.w;
            x1[4]=b1.x; x1[5]=b1.y; x1[6]=b1.z; x1[7]=b1.w;
            x1[8]=b2.x; x1[9]=b2.y; x1[10]=b2.z; x1[11]=b2.w;
            x1[12]=b3.x; x1[13]=b3.y; x1[14]=b3.z; x1[15]=b3.w;
        }
        #pragma unroll
        for (int o = 0; o < 16; ++o) {
            const float4 w0 = ((const float4*)&s_w[o*16])[0];
            const float4 w1 = ((const float4*)&s_w[o*16])[1];
            const float4 w2 = ((const float4*)&s_w[o*16])[2];
            const float4 w3 = ((const float4*)&s_w[o*16])[3];
            const float b = s_b[o];
            float a0 = b, a1 = b;
            a0=fmaf(x0[0],w0.x,a0); a0=fmaf(x0[1],w0.y,a0); a0=fmaf(x0[2],w0.z,a0); a0=fmaf(x0[3],w0.w,a0);
            a0=fmaf(x0[4],w1.x,a0); a0=fmaf(x0[5],w1.y,a0); a0=fmaf(x0[6],w1.z,a0); a0=fmaf(x0[7],w1.w,a0);
            a0=fmaf(x0[8],w2.x,a0); a0=fmaf(x0[9],w2.y,a0); a0=fmaf(x0[10],w2.z,a0); a0=fmaf(x0[11],w2.w,a0);
            a0=fmaf(x0[12],w3.x,a0); a0=fmaf(x0[13],w3.y,a0); a0=fmaf(x0[14],w3.z,a0); a0=fmaf(x0[15],w3.w,a0);
            a1=fmaf(x1[0],w0.x,a1); a1=fmaf(x1[1],w0.y,a1); a1=fmaf(x1[2],w0.z,a1); a1=fmaf(x1[3],w0.w,a1);
            a1=fmaf(x1[4],w1.x,a1); a1=fmaf(x1[5],w1.y,a1); a1=fmaf(x1[6],w1.z,a1); a1=fmaf(x1[7],w1.w,a1);
            a1=fmaf(x1[8],w2.x,a1); a1=fmaf(x1[9],w2.y,a1); a1=fmaf(x1[10],w2.z,a1); a1=fmaf(x1[11],w2.w,a1);
            a1=fmaf(x1[12],w3.x,a1); a1=fmaf(x1[13],w3.y,a1); a1=fmaf(x1[14],w3.z,a1); a1=fmaf(x1[15],w3.w,a1);
            q0[o] = a0 * SCALE_LOG2E;
            q1[o] = a1 * SCALE_LOG2E;
        }
    }
    {
        int kvrow = -1, base = 16;
        if (t < K_)                        { kvrow = t;       base = 16; }  // K row
        else if (t >= 256 && t < 256 + K_) { kvrow = t - 256; base = 32; }  // V row
        if (kvrow >= 0) {
            const float4* xs4 = (const float4*)&s_x[kvrow][0];
            const float4 a0 = xs4[0], a1 = xs4[1], a2 = xs4[2], a3 = xs4[3];
            const float xs[16] = {a0.x,a0.y,a0.z,a0.w, a1.x,a1.y,a1.z,a1.w,
                                  a2.x,a2.y,a2.z,a2.w, a3.x,a3.y,a3.z,a3.w};
            float kv[16];
            #pragma unroll
            for (int o = 0; o < 16; ++o) {
                const float* wr = &s_w[(base + o)*16];
                const float4 w0 = ((const float4*)wr)[0];
                const float4 w1 = ((const float4*)wr)[1];
                const float4 w2 = ((const float4*)wr)[2];
                const float4 w3 = ((const float4*)wr)[3];
                float sv = s_b[base + o];
                sv=fmaf(xs[0],w0.x,sv); sv=fmaf(xs[1],w0.y,sv); sv=fmaf(xs[2],w0.z,sv); sv=fmaf(xs[3],w0.w,sv);
                sv=fmaf(xs[4],w1.x,sv); sv=fmaf(xs[5],w1.y,sv); sv=fmaf(xs[6],w1.z,sv); sv=fmaf(xs[7],w1.w,sv);
                sv=fmaf(xs[8],w2.x,sv); sv=fmaf(xs[9],w2.y,sv); sv=fmaf(xs[10],w2.z,sv); sv=fmaf(xs[11],w2.w,sv);
                sv=fmaf(xs[12],w3.x,sv); sv=fmaf(xs[13],w3.y,sv); sv=fmaf(xs[14],w3.z,sv); sv=fmaf(xs[15],w3.w,sv);
                kv[o] = sv;
            }
            float* dst = (base == 16) ? &s_k[kvrow][0] : &s_v[kvrow][0];
            ((float4*)dst)[0] = make_float4(kv[0],kv[1],kv[2],kv[3]);
            ((float4*)dst)[1] = make_float4(kv[4],kv[5],kv[6],kv[7]);
            ((float4*)dst)[2] = make_float4(kv[8],kv[9],kv[10],kv[11]);
            ((float4*)dst)[3] = make_float4(kv[12],kv[13],kv[14],kv[15]);
        }
    }
    __syncthreads();

    // ---- attention: 2 queries x keys {e, e+8, ...}; max-free softmax ----
    if (qact) {
        float acc0[16], acc1[16];
        #pragma unroll
        for (int i = 0; i < 16; ++i) { acc0[i] = 0.0f; acc1[i] = 0.0f; }
        float ls0=0.f, ls1=0.f, ls2=0.f, ls3=0.f, ls4=0.f, ls5=0.f, ls6=0.f, ls7=0.f;

        const float* kp  = &s_k[e][0];
        const float* vp2 = &s_v[e][0];
        const int n = 31 + ((e < 2) ? 1 : 0);   // keys e+8*jj <= 249
        #pragma unroll 2
        for (int jj = 0; jj < n; ++jj) {
            ATT_STEP(kp, vp2);
            kp += 8*SK; vp2 += 8*SK;
        }

        // combine the 8 key-eighths (lanes e^1, e^2, e^4)
        #pragma unroll
        for (int m = 1; m <= 4; m <<= 1) {
            #pragma unroll
            for (int i = 0; i < 16; ++i) {
                acc0[i] += __shfl_xor(acc0[i], m);
                acc1[i] += __shfl_xor(acc1[i], m);
            }
            ls0 += __shfl_xor(ls0,m); ls1 += __shfl_xor(ls1,m);
            ls2 += __shfl_xor(ls2,m); ls3 += __shfl_xor(ls3,m);
            ls4 += __shfl_xor(ls4,m); ls5 += __shfl_xor(ls5,m);
            ls6 += __shfl_xor(ls6,m); ls7 += __shfl_xor(ls7,m);
        }

        const float i00 = __builtin_amdgcn_rcpf(ls0);
        const float i01 = __builtin_amdgcn_rcpf(ls1);
        const float i02 = __builtin_amdgcn_rcpf(ls2);
        const float i03 = __builtin_amdgcn_rcpf(ls3);
        const float i10 = __builtin_amdgcn_rcpf(ls4);
        const float i11 = __builtin_amdgcn_rcpf(ls5);
        const float i12 = __builtin_amdgcn_rcpf(ls6);
        const float i13 = __builtin_amdgcn_rcpf(ls7);
        float o0[16], o1[16];
        o0[0]=acc0[0]*i00;  o0[1]=acc0[1]*i00;  o0[2]=acc0[2]*i00;  o0[3]=acc0[3]*i00;
        o0[4]=acc0[4]*i01;  o0[5]=acc0[5]*i01;  o0[6]=acc0[6]*i01;  o0[7]=acc0[7]*i01;
        o0[8]=acc0[8]*i02;  o0[9]=acc0[9]*i02;  o0[10]=acc0[10]*i02; o0[11]=acc0[11]*i02;
        o0[12]=acc0[12]*i03; o0[13]=acc0[13]*i03; o0[14]=acc0[14]*i03; o0[15]=acc0[15]*i03;
        o1[0]=acc1[0]*i10;  o1[1]=acc1[1]*i10;  o1[2]=acc1[2]*i10;  o1[3]=acc1[3]*i10;
        o1[4]=acc1[4]*i11;  o1[5]=acc1[5]*i11;  o1[6]=acc1[6]*i11;  o1[7]=acc1[7]*i11;
        o1[8]=acc1[8]*i12;  o1[9]=acc1[9]*i12;  o1[10]=acc1[10]*i12; o1[11]=acc1[11]*i12;
        o1[12]=acc1[12]*i13; o1[13]=acc1[13]*i13; o1[14]=acc1[14]*i13; o1[15]=acc1[15]*i13;

        // epilogue: lane computes output dims od,od+1 of both query rows
        float y0[2], y1[2];
        #pragma unroll
        for (int c = 0; c < 2; ++c) {
            const float* wr = &s_ow[(od + c)*16];
            const float4 w0 = ((const float4*)wr)[0];
            const float4 w1 = ((const float4*)wr)[1];
            const float4 w2 = ((const float4*)wr)[2];
            const float4 w3 = ((const float4*)wr)[3];
            const float b = s_ob[od + c];
            float a0 = b, a1 = b;
            a0=fmaf(o0[0],w0.x,a0); a0=fmaf(o0[1],w0.y,a0); a0=fmaf(o0[2],w0.z,a0); a0=fmaf(o0[3],w0.w,a0);
            a0=fmaf(o0[4],w1.x,a0); a0=fmaf(o0[5],w1.y,a0); a0=fmaf(o0[6],w1.z,a0); a0=fmaf(o0[7],w1.w,a0);
            a0=fmaf(o0[8],w2.x,a0); a0=fmaf(o0[9],w2.y,a0); a0=fmaf(o0[10],w2.z,a0); a0=fmaf(o0[11],w2.w,a0);
            a0=fmaf(o0[12],w3.x,a0); a0=fmaf(o0[13],w3.y,a0); a0=fmaf(o0[14],w3.z,a0); a0=fmaf(o0[15],w3.w,a0);
            a1=fmaf(o1[0],w0.x,a1); a1=fmaf(o1[1],w0.y,a1); a1=fmaf(o1[2],w0.z,a1); a1=fmaf(o1[3],w0.w,a1);
            a1=fmaf(o1[4],w1.x,a1); a1=fmaf(o1[5],w1.y,a1); a1=fmaf(o1[6],w1.z,a1); a1=fmaf(o1[7],w1.w,a1);
            a1=fmaf(o1[8],w2.x,a1); a1=fmaf(o1[9],w2.y,a1); a1=fmaf(o1[10],w2.z,a1); a1=fmaf(o1[11],w2.w,a1);
            a1=fmaf(o1[12],w3.x,a1); a1=fmaf(o1[13],w3.y,a1); a1=fmaf(o1[14],w3.z,a1); a1=fmaf(o1[15],w3.w,a1);
            y0[c] = a0; y1[c] = a1;
        }
        // residual + LayerNorm; stats via 8-lane xor reduce (2 dims per lane x 8 = 16)
        const float2 xr0 = *(const float2*)&s_x[arow][od];
        const float2 xr1 = *(const float2*)&s_x[brow][od];
        const float t00 = y0[0]+xr0.x, t01 = y0[1]+xr0.y;
        const float t10 = y1[0]+xr1.x, t11 = y1[1]+xr1.y;
        float sum0 = t00+t01,               sum1 = t10+t11;
        float sq0  = fmaf(t00,t00,t01*t01), sq1  = fmaf(t10,t10,t11*t11);
        #pragma unroll
        for (int m = 1; m <= 4; m <<= 1) {
            sum0 += __shfl_xor(sum0,m); sq0 += __shfl_xor(sq0,m);
            sum1 += __shfl_xor(sum1,m); sq1 += __shfl_xor(sq1,m);
        }
        const float mu0 = sum0 * 0.0625f;
        const float mu1 = sum1 * 0.0625f;
        const float var0 = fmaf(-mu0, mu0, sq0 * 0.0625f);
        const float var1 = fmaf(-mu1, mu1, sq1 * 0.0625f);
        const float rs0 = __builtin_amdgcn_rsqf(var0 + 1e-5f);
        const float rs1 = __builtin_amdgcn_rsqf(var1 + 1e-5f);
        const float2 g  = *(const float2*)&s_lng[od];
        const float2 bb = *(const float2*)&s_lnb[od];
        float2 xn0, xn1;
        xn0.x = (t00-mu0)*rs0*g.x + bb.x;  xn0.y = (t01-mu0)*rs0*g.y + bb.y;
        xn1.x = (t10-mu1)*rs1*g.x + bb.x;  xn1.y = (t11-mu1)*rs1*g.y + bb.y;
        float* oa = xout + ((size_t)r*K_ + arow)*16 + od;
        *(float2*)oa = xn0;
        if (bval) {
            float* ob = xout + ((size_t)r*K_ + brow)*16 + od;
            *(float2*)ob = xn1;
        }
    }
}

extern "C" void kernel_launch(void* const* d_in, const int* in_sizes, int n_in,
                              void* d_out, int out_size, void* d_ws, size_t ws_size,
                              hipStream_t stream) {
    const float* pv      = (const float*)d_in[0];
    const int*   ele_idx = (const int*)  d_in[1];
    const int*   azi_idx = (const int*)  d_in[2];
    const float* vp_w    = (const float*)d_in[3];
    const float* vp_b    = (const float*)d_in[4];
    const float* ele_emb = (const float*)d_in[5];
    const float* azi_emb = (const float*)d_in[6];
    const float* ipw     = (const float*)d_in[7];
    const float* ipb     = (const float*)d_in[8];
    const float* outw    = (const float*)d_in[9];
    const float* outb    = (const float*)d_in[10];
    const float* lng     = (const float*)d_in[11];
    const float* lnb     = (const float*)d_in[12];
    float* out = (float*)d_out;
    float* xws = (float*)d_ws;          // layer-0 output handoff: R*K*16 f32 = 8.192 MB

    mlra_pass<0><<<2*R_, 512, 0, stream>>>(pv, ele_idx, azi_idx, vp_w, vp_b,
                                           ele_emb, azi_emb, ipw, ipb,
                                           outw, outb, lng, lnb, nullptr, xws);
    mlra_pass<1><<<2*R_, 512, 0, stream>>>(pv, ele_idx, azi_idx, vp_w, vp_b,
                                           ele_emb, azi_emb, ipw, ipb,
                                           outw, outb, lng, lnb, xws, out);
}

// Round 8
// 188.600 us; speedup vs baseline: 1.1336x; 1.1336x over previous
//
#include <hip/hip_runtime.h>

#define R_ 512
#define K_ 250
#define SCALE_LOG2E 0.72134752044448170f

// thread = (qg, hp, ks): qg = t>>3 (4 query rows), hp = (t>>2)&1 (dims 8hp..8hp+8,
// i.e. heads 2hp,2hp+1), ks = t&3 (keys j == ks mod 4). Attention reads only the
// thread's 8-dim half of each K/V row: 4 ds_read_b128 per key covering 4 queries.
__global__ __launch_bounds__(512, 2)
void mlra_kernel(const float* __restrict__ pv,       // [R*K,8]
                 const int*   __restrict__ ele_idx,  // [R*K]
                 const int*   __restrict__ azi_idx,  // [R*K]
                 const float* __restrict__ vp_w,     // [8,8]
                 const float* __restrict__ vp_b,     // [8]
                 const float* __restrict__ ele_emb,  // [37,4]
                 const float* __restrict__ azi_emb,  // [107,4]
                 const float* __restrict__ ipw,      // [2,48,16]
                 const float* __restrict__ ipb,      // [2,48]
                 const float* __restrict__ outw,     // [2,16,16]
                 const float* __restrict__ outb,     // [2,16]
                 const float* __restrict__ lng,      // [16]
                 const float* __restrict__ lnb,      // [16]
                 float* __restrict__ out)            // [R*K,16]
{
    __shared__ float s_k[K_][16];       // 16000 B, stride 64B: ks/hp lanes -> 2-way max (free)
    __shared__ float s_v[K_][16];       // 16000 B
    __shared__ float s_x[256][20];      // 20480 B (rows 250..255 zeroed for masked tail)
    __shared__ float s_w[768];
    __shared__ float s_b[48];
    __shared__ float s_ow[256];
    __shared__ float s_ob[16];
    __shared__ float s_vpw[64];
    __shared__ float s_vpb[8];
    __shared__ float s_ele[148];
    __shared__ float s_azi[428];
    __shared__ float s_lng[16], s_lnb[16];

    const int r = blockIdx.x;
    const int t = threadIdx.x;

    if (t < 64) s_vpw[t] = vp_w[t];
    if (t >= 64 && t < 72) s_vpb[t - 64] = vp_b[t - 64];
    for (int i = t; i < 148; i += 512) s_ele[i] = ele_emb[i];
    for (int i = t; i < 428; i += 512) s_azi[i] = azi_emb[i];
    if (t < 16) { s_lng[t] = lng[t]; s_lnb[t] = lnb[t]; }
    __syncthreads();

    // ---- prologue: x rows 0..249; zero rows 250..255 ----
    if (t < K_) {
        const size_t row = (size_t)r * K_ + t;
        const float4 p0 = ((const float4*)(pv + row * 8))[0];
        const float4 p1 = ((const float4*)(pv + row * 8))[1];
        const float a[8] = {p0.x,p0.y,p0.z,p0.w,p1.x,p1.y,p1.z,p1.w};
        float xr[16];
        #pragma unroll
        for (int o = 0; o < 8; ++o) {
            const float4 w0 = ((const float4*)&s_vpw[o*8])[0];
            const float4 w1 = ((const float4*)&s_vpw[o*8])[1];
            float sv = s_vpb[o];
            sv = fmaf(a[0],w0.x,sv); sv = fmaf(a[1],w0.y,sv); sv = fmaf(a[2],w0.z,sv); sv = fmaf(a[3],w0.w,sv);
            sv = fmaf(a[4],w1.x,sv); sv = fmaf(a[5],w1.y,sv); sv = fmaf(a[6],w1.z,sv); sv = fmaf(a[7],w1.w,sv);
            xr[o] = sv;
        }
        const int ei = ele_idx[row];
        const int ai = azi_idx[row];
        const float4 ee = *(const float4*)&s_ele[ei*4];
        const float4 ae = *(const float4*)&s_azi[ai*4];
        xr[8]=ee.x; xr[9]=ee.y; xr[10]=ee.z; xr[11]=ee.w;
        xr[12]=ae.x; xr[13]=ae.y; xr[14]=ae.z; xr[15]=ae.w;
        *(float4*)&s_x[t][0]  = make_float4(xr[0],xr[1],xr[2],xr[3]);
        *(float4*)&s_x[t][4]  = make_float4(xr[4],xr[5],xr[6],xr[7]);
        *(float4*)&s_x[t][8]  = make_float4(xr[8],xr[9],xr[10],xr[11]);
        *(float4*)&s_x[t][12] = make_float4(xr[12],xr[13],xr[14],xr[15]);
    } else if (t < 256) {
        const float4 z = make_float4(0.f,0.f,0.f,0.f);
        *(float4*)&s_x[t][0] = z; *(float4*)&s_x[t][4] = z;
        *(float4*)&s_x[t][8] = z; *(float4*)&s_x[t][12] = z;
    }

    const int qg = t >> 3;
    const int hp = (t >> 2) & 1;
    const int ks = t & 3;
    const int rbase = 4 * qg;

    for (int l = 0; l < 2; ++l) {
        __syncthreads();   // prev-layer epilogue / prologue done before weight overwrite
        for (int i = t; i < 768; i += 512) s_w[i] = ipw[l*768 + i];
        if (t < 48)  s_b[t]  = ipb[l*48 + t];
        if (t < 256) s_ow[t] = outw[l*256 + t];
        if (t < 16)  s_ob[t] = outb[l*16 + t];
        __syncthreads();

        // ---- q: 4 queries x own 8 dims; ks-split partials + quad combine ----
        float q[4][8];
        {
            const float4 xq0 = *(const float4*)&s_x[rbase+0][4*ks];
            const float4 xq1 = *(const float4*)&s_x[rbase+1][4*ks];
            const float4 xq2 = *(const float4*)&s_x[rbase+2][4*ks];
            const float4 xq3 = *(const float4*)&s_x[rbase+3][4*ks];
            #pragma unroll
            for (int oo = 0; oo < 8; ++oo) {
                const int o = 8*hp + oo;
                const float4 w = *(const float4*)&s_w[o*16 + 4*ks];
                float p0 = fmaf(xq0.x,w.x, fmaf(xq0.y,w.y, fmaf(xq0.z,w.z, xq0.w*w.w)));
                float p1 = fmaf(xq1.x,w.x, fmaf(xq1.y,w.y, fmaf(xq1.z,w.z, xq1.w*w.w)));
                float p2 = fmaf(xq2.x,w.x, fmaf(xq2.y,w.y, fmaf(xq2.z,w.z, xq2.w*w.w)));
                float p3 = fmaf(xq3.x,w.x, fmaf(xq3.y,w.y, fmaf(xq3.z,w.z, xq3.w*w.w)));
                p0 += __shfl_xor(p0,1); p0 += __shfl_xor(p0,2);
                p1 += __shfl_xor(p1,1); p1 += __shfl_xor(p1,2);
                p2 += __shfl_xor(p2,1); p2 += __shfl_xor(p2,2);
                p3 += __shfl_xor(p3,1); p3 += __shfl_xor(p3,2);
                const float bo = s_b[o];
                q[0][oo] = (p0 + bo) * SCALE_LOG2E;
                q[1][oo] = (p1 + bo) * SCALE_LOG2E;
                q[2][oo] = (p2 + bo) * SCALE_LOG2E;
                q[3][oo] = (p3 + bo) * SCALE_LOG2E;
            }
        }

        // ---- K/V staging: thread t<250 -> K row t; 256<=t<506 -> V row t-256 ----
        {
            int kvrow = -1, base = 16;
            if (t < K_)                        { kvrow = t;       base = 16; }
            else if (t >= 256 && t < 256 + K_) { kvrow = t - 256; base = 32; }
            if (kvrow >= 0) {
                const float4 xa = *(const float4*)&s_x[kvrow][0];
                const float4 xb = *(const float4*)&s_x[kvrow][4];
                const float4 xc = *(const float4*)&s_x[kvrow][8];
                const float4 xd = *(const float4*)&s_x[kvrow][12];
                float kvv[16];
                #pragma unroll
                for (int o = 0; o < 16; ++o) {
                    const float* wr = &s_w[(base + o)*16];
                    const float4 w0 = ((const float4*)wr)[0];
                    const float4 w1 = ((const float4*)wr)[1];
                    const float4 w2 = ((const float4*)wr)[2];
                    const float4 w3 = ((const float4*)wr)[3];
                    float sv = s_b[base + o];
                    sv=fmaf(xa.x,w0.x,sv); sv=fmaf(xa.y,w0.y,sv); sv=fmaf(xa.z,w0.z,sv); sv=fmaf(xa.w,w0.w,sv);
                    sv=fmaf(xb.x,w1.x,sv); sv=fmaf(xb.y,w1.y,sv); sv=fmaf(xb.z,w1.z,sv); sv=fmaf(xb.w,w1.w,sv);
                    sv=fmaf(xc.x,w2.x,sv); sv=fmaf(xc.y,w2.y,sv); sv=fmaf(xc.z,w2.z,sv); sv=fmaf(xc.w,w2.w,sv);
                    sv=fmaf(xd.x,w3.x,sv); sv=fmaf(xd.y,w3.y,sv); sv=fmaf(xd.z,w3.z,sv); sv=fmaf(xd.w,w3.w,sv);
                    kvv[o] = sv;
                }
                float* dst = (base == 16) ? &s_k[kvrow][0] : &s_v[kvrow][0];
                *(float4*)&dst[0]  = make_float4(kvv[0],kvv[1],kvv[2],kvv[3]);
                *(float4*)&dst[4]  = make_float4(kvv[4],kvv[5],kvv[6],kvv[7]);
                *(float4*)&dst[8]  = make_float4(kvv[8],kvv[9],kvv[10],kvv[11]);
                *(float4*)&dst[12] = make_float4(kvv[12],kvv[13],kvv[14],kvv[15]);
            }
        }
        __syncthreads();

        // ---- attention: 4 queries x 2 heads x keys {ks, ks+4, ...} ----
        float acc[4][8];
        float ls[4][2];
        #pragma unroll
        for (int i = 0; i < 4; ++i) {
            ls[i][0] = 0.f; ls[i][1] = 0.f;
            #pragma unroll
            for (int d = 0; d < 8; ++d) acc[i][d] = 0.f;
        }
        {
            const float* kp  = &s_k[ks][8*hp];
            const float* vp2 = &s_v[ks][8*hp];
            const int n = 63 - (ks >> 1);    // ks 0,1: 63 keys; ks 2,3: 62
            #pragma unroll 2
            for (int jj = 0; jj < n; ++jj) {
                const float4 ka = ((const float4*)kp)[0];
                const float4 kb = ((const float4*)kp)[1];
                const float4 va = ((const float4*)vp2)[0];
                const float4 vb = ((const float4*)vp2)[1];
                #pragma unroll
                for (int i = 0; i < 4; ++i) {
                    const float sA = fmaf(q[i][0],ka.x, fmaf(q[i][1],ka.y, fmaf(q[i][2],ka.z, q[i][3]*ka.w)));
                    const float sB = fmaf(q[i][4],kb.x, fmaf(q[i][5],kb.y, fmaf(q[i][6],kb.z, q[i][7]*kb.w)));
                    const float pA = __builtin_amdgcn_exp2f(sA);
                    const float pB = __builtin_amdgcn_exp2f(sB);
                    ls[i][0] += pA; ls[i][1] += pB;
                    acc[i][0]=fmaf(pA,va.x,acc[i][0]); acc[i][1]=fmaf(pA,va.y,acc[i][1]);
                    acc[i][2]=fmaf(pA,va.z,acc[i][2]); acc[i][3]=fmaf(pA,va.w,acc[i][3]);
                    acc[i][4]=fmaf(pB,vb.x,acc[i][4]); acc[i][5]=fmaf(pB,vb.y,acc[i][5]);
                    acc[i][6]=fmaf(pB,vb.z,acc[i][6]); acc[i][7]=fmaf(pB,vb.w,acc[i][7]);
                }
                kp += 64; vp2 += 64;
            }
        }

        // ---- ks-combine (quad) + softmax normalize ----
        #pragma unroll
        for (int i = 0; i < 4; ++i) {
            #pragma unroll
            for (int d = 0; d < 8; ++d) {
                float v = acc[i][d];
                v += __shfl_xor(v,1); v += __shfl_xor(v,2);
                acc[i][d] = v;
            }
            float a = ls[i][0]; a += __shfl_xor(a,1); a += __shfl_xor(a,2);
            float b = ls[i][1]; b += __shfl_xor(b,1); b += __shfl_xor(b,2);
            const float ra = __builtin_amdgcn_rcpf(a);
            const float rb = __builtin_amdgcn_rcpf(b);
            acc[i][0]*=ra; acc[i][1]*=ra; acc[i][2]*=ra; acc[i][3]*=ra;
            acc[i][4]*=rb; acc[i][5]*=rb; acc[i][6]*=rb; acc[i][7]*=rb;
        }

        // ---- out-proj: lane owns outdims [4ks..4ks+4); partial over own 8 indims ----
        float yv[4][4];   // [query][c]
        #pragma unroll
        for (int c = 0; c < 4; ++c) {
            const int oq = 4*ks + c;
            const float4 wA = *(const float4*)&s_ow[oq*16 + 8*hp];
            const float4 wB = *(const float4*)&s_ow[oq*16 + 8*hp + 4];
            #pragma unroll
            for (int i = 0; i < 4; ++i) {
                float p = fmaf(acc[i][0],wA.x, fmaf(acc[i][1],wA.y, fmaf(acc[i][2],wA.z, acc[i][3]*wA.w)));
                p = fmaf(acc[i][4],wB.x, fmaf(acc[i][5],wB.y, fmaf(acc[i][6],wB.z, fmaf(acc[i][7],wB.w, p))));
                yv[i][c] = p;
            }
        }
        #pragma unroll
        for (int i = 0; i < 4; ++i) {
            #pragma unroll
            for (int c = 0; c < 4; ++c) {
                float p = yv[i][c];
                p += __shfl_xor(p, 4);           // combine head-pair halves
                yv[i][c] = p + s_ob[4*ks + c];
            }
        }

        // ---- residual + LN (stats via quad reduce over ks; hp duplicates) ----
        const float4 g4 = *(const float4*)&s_lng[4*ks];
        const float4 b4 = *(const float4*)&s_lnb[4*ks];
        #pragma unroll
        for (int i = 0; i < 4; ++i) {
            const int row = rbase + i;
            const float4 xr = *(const float4*)&s_x[row][4*ks];
            const float t0 = yv[i][0]+xr.x, t1 = yv[i][1]+xr.y;
            const float t2 = yv[i][2]+xr.z, t3 = yv[i][3]+xr.w;
            float sm = (t0+t1)+(t2+t3);
            float sq = fmaf(t0,t0, fmaf(t1,t1, fmaf(t2,t2, t3*t3)));
            sm += __shfl_xor(sm,1); sm += __shfl_xor(sm,2);
            sq += __shfl_xor(sq,1); sq += __shfl_xor(sq,2);
            const float mu  = sm * 0.0625f;
            const float var = fmaf(-mu, mu, sq * 0.0625f);
            const float rs  = __builtin_amdgcn_rsqf(var + 1e-5f);
            float4 xn;
            xn.x = (t0-mu)*rs*g4.x + b4.x;
            xn.y = (t1-mu)*rs*g4.y + b4.y;
            xn.z = (t2-mu)*rs*g4.z + b4.z;
            xn.w = (t3-mu)*rs*g4.w + b4.w;
            if (l == 0) {
                *(float4*)&s_x[row][4*ks] = xn;          // hp0/hp1 write identical bits
            } else if (hp == 0 && row < K_) {
                *(float4*)&out[((size_t)r*K_ + row)*16 + 4*ks] = xn;
            }
        }
    }
}

extern "C" void kernel_launch(void* const* d_in, const int* in_sizes, int n_in,
                              void* d_out, int out_size, void* d_ws, size_t ws_size,
                              hipStream_t stream) {
    const float* pv      = (const float*)d_in[0];
    const int*   ele_idx = (const int*)  d_in[1];
    const int*   azi_idx = (const int*)  d_in[2];
    const float* vp_w    = (const float*)d_in[3];
    const float* vp_b    = (const float*)d_in[4];
    const float* ele_emb = (const float*)d_in[5];
    const float* azi_emb = (const float*)d_in[6];
    const float* ipw     = (const float*)d_in[7];
    const float* ipb     = (const float*)d_in[8];
    const float* outw    = (const float*)d_in[9];
    const float* outb    = (const float*)d_in[10];
    const float* lng     = (const float*)d_in[11];
    const float* lnb     = (const float*)d_in[12];
    float* out = (float*)d_out;

    mlra_kernel<<<R_, 512, 0, stream>>>(pv, ele_idx, azi_idx, vp_w, vp_b,
                                        ele_emb, azi_emb, ipw, ipb,
                                        outw, outb, lng, lnb, out);
}